// Round 1
// baseline (330.280 us; speedup 1.0000x reference)
//
#include <hip/hip_runtime.h>

#define BDIM   256
#define BPB    4      // boards per block (4*729 floats = 11664 B, 16B-aligned groups)
#define KK     9
#define CELLS  81
#define BOARD  729
#define CHUNK  (BPB * BOARD)   // 2916 floats = 729 float4

__global__ __launch_bounds__(BDIM) void sudoku_iter_kernel(
    const float* __restrict__ sudoku,
    const float* __restrict__ rmask,
    const float* __restrict__ rindex,
    const float* __restrict__ conv_w,
    const float* __restrict__ conv_b,
    float* __restrict__ out,
    int Btot)
{
    __shared__ float lds_s[CHUNK];           // 11664 B
    __shared__ int   meta_e[BPB];            // chosen element index (n*81+cell) per board
    __shared__ int   meta_cell[BPB];         // chosen cell per board
    __shared__ float meta_m[BPB];            // max value at chosen cell
    __shared__ float meta_cms[BPB];          // clip(m*w[n*]+bias, 0,1)
    __shared__ float meta_ri[BPB];           // recursion_index per board

    const int tid   = threadIdx.x;
    const int block = blockIdx.x;
    const size_t base = (size_t)block * CHUNK;   // flat float offset of this block's 4 boards

    // conv weights (9 floats) + bias — L1/L2 broadcast
    float wreg[KK];
    #pragma unroll
    for (int n = 0; n < KK; ++n) wreg[n] = conv_w[n];
    const float bias = conv_b[0];
    const float cmp  = fminf(fmaxf(bias, 0.f), 1.f);   // cell_mask away from chosen cell

    // ---- stage 4 boards into LDS via float4 (fully coalesced, 16B-aligned) ----
    const float4* gsrc = (const float4*)(sudoku + base);
    float4* lds4 = (float4*)lds_s;
    #pragma unroll
    for (int i = 0; i < 3; ++i) {
        int g = tid + i * BDIM;
        if (g < CHUNK / 4) lds4[g] = gsrc[g];
    }
    __syncthreads();

    // ---- per-board selection: wave w handles board w ----
    {
        const int wave = tid >> 6;
        const int lane = tid & 63;
        const float* bs = lds_s + wave * BOARD;

        // candidate-count value per cell; lane handles cell=lane and cell=lane+64
        float v0; int i0;
        {
            const int cell = lane;
            float cnt = bias;
            #pragma unroll
            for (int n = 0; n < KK; ++n) cnt += bs[n * CELLS + cell] * wreg[n];
            float nic = fmaxf(cnt - 1.f, 0.f);                       // relu(conv-1)
            float m0  = fminf(fmaxf(1.f - nic, 0.f), 1.f) * (-(float)KK);
            v0 = m0 - nic; i0 = cell;
        }
        if (lane < CELLS - 64) {     // cells 64..80
            const int cell = lane + 64;
            float cnt = bias;
            #pragma unroll
            for (int n = 0; n < KK; ++n) cnt += bs[n * CELLS + cell] * wreg[n];
            float nic = fmaxf(cnt - 1.f, 0.f);
            float m0  = fminf(fmaxf(1.f - nic, 0.f), 1.f) * (-(float)KK);
            float v1 = m0 - nic;
            if (v1 > v0) { v0 = v1; i0 = cell; }   // tie keeps smaller index
        }
        // butterfly argmax-first over 64 lanes (max value; tie -> smaller cell index)
        #pragma unroll
        for (int off = 32; off > 0; off >>= 1) {
            float ov = __shfl_xor(v0, off, 64);
            int   oi = __shfl_xor(i0, off, 64);
            if (ov > v0 || (ov == v0 && oi < i0)) { v0 = ov; i0 = oi; }
        }
        if (lane == 0) {
            const int cell = i0;
            // first-argmax over numbers at chosen cell
            float m = bs[cell]; int nstar = 0;
            #pragma unroll
            for (int n = 1; n < KK; ++n) {
                float v = bs[n * CELLS + cell];
                if (v > m) { m = v; nstar = n; }
            }
            meta_e[wave]    = nstar * CELLS + cell;
            meta_cell[wave] = cell;
            meta_m[wave]    = m;
            meta_cms[wave]  = fminf(fmaxf(m * wreg[nstar] + bias, 0.f), 1.f);
            meta_ri[wave]   = rindex[block * BPB + wave];
        }
    }
    __syncthreads();

    // ---- elementwise epilogue: float4 in (rmask) / float4 out (sudoku_out, rmask_out) ----
    const float4* grm4   = (const float4*)(rmask + base);
    float4*       gout_s = (float4*)(out + base);
    float4*       gout_r = (float4*)(out + (size_t)Btot * BOARD + base);

    #pragma unroll
    for (int i = 0; i < 3; ++i) {
        int g = tid + i * BDIM;
        if (g < CHUNK / 4) {
            float4 s4 = lds4[g];
            float4 r4 = grm4[g];
            float so[4], ro[4];
            const float* sp = (const float*)&s4;
            const float* rp = (const float*)&r4;
            #pragma unroll
            for (int j = 0; j < 4; ++j) {
                int f = 4 * g + j;                         // 0..2915
                int bl = (f >= 1458) ? (f >= 2187 ? 3 : 2) : (f >= 729 ? 1 : 0);
                int e = f - bl * BOARD;                    // 0..728 within board
                int cell = e % CELLS;                      // magic-mul const div
                float s  = sp[j];
                float rm = rp[j];
                float m   = meta_m[bl];
                float riv = meta_ri[bl];
                float ov  = (e == meta_e[bl]) ? m : 0.f;                 // one_variant
                float cm  = (cell == meta_cell[bl]) ? meta_cms[bl] : cmp; // cell_mask
                float orm = s * cm * (1.f - ov);                          // one_recursion_mask
                float rmo = fmaxf(rm, riv * orm);
                rmo = fmaxf(rmo, (riv - 1.f) * ov);
                so[j] = s * (1.f - orm);
                ro[j] = rmo;
            }
            gout_s[g] = make_float4(so[0], so[1], so[2], so[3]);
            gout_r[g] = make_float4(ro[0], ro[1], ro[2], ro[3]);
        }
    }

    // recursion_index + 1 output (one float per board)
    if (tid < BPB) {
        out[(size_t)Btot * BOARD * 2 + (size_t)block * BPB + tid] = meta_ri[tid] + 1.f;
    }
}

extern "C" void kernel_launch(void* const* d_in, const int* in_sizes, int n_in,
                              void* d_out, int out_size, void* d_ws, size_t ws_size,
                              hipStream_t stream) {
    const float* sudoku = (const float*)d_in[0];
    const float* rmask  = (const float*)d_in[1];
    const float* rindex = (const float*)d_in[2];
    const float* conv_w = (const float*)d_in[3];
    const float* conv_b = (const float*)d_in[4];
    float* out = (float*)d_out;

    const int Btot = in_sizes[2];            // 32768 boards
    const int nblocks = Btot / BPB;          // 8192

    sudoku_iter_kernel<<<nblocks, BDIM, 0, stream>>>(
        sudoku, rmask, rindex, conv_w, conv_b, out, Btot);
}

// Round 3
// 316.624 us; speedup vs baseline: 1.0431x; 1.0431x over previous
//
#include <hip/hip_runtime.h>

#define BDIM   256
#define BPB    4      // boards per block (4*729 floats = 11664 B, 16B-aligned groups)
#define KK     9
#define CELLS  81
#define BOARD  729
#define CHUNK  (BPB * BOARD)   // 2916 floats = 729 float4
#define NV4    3               // float4 iterations per thread: ceil(729/256)

typedef float v4f __attribute__((ext_vector_type(4)));   // native vector: OK for nontemporal builtins

__global__ __launch_bounds__(BDIM) void sudoku_iter_kernel(
    const float* __restrict__ sudoku,
    const float* __restrict__ rmask,
    const float* __restrict__ rindex,
    const float* __restrict__ conv_w,
    const float* __restrict__ conv_b,
    float* __restrict__ out,
    int Btot)
{
    __shared__ float lds_s[CHUNK];           // 11664 B
    __shared__ int   meta_e[BPB];            // chosen element index (n*81+cell) per board
    __shared__ int   meta_cell[BPB];         // chosen cell per board
    __shared__ float meta_m[BPB];            // max value at chosen cell
    __shared__ float meta_cms[BPB];          // clip(m*w[n*]+bias, 0,1)
    __shared__ float meta_ri[BPB];           // recursion_index per board

    const int tid   = threadIdx.x;
    const int block = blockIdx.x;
    const size_t base = (size_t)block * CHUNK;

    // ---- issue ALL global loads up front: sudoku first (LDS stage waits only on
    // these), then rmask (stays in flight across both barriers) ----
    const v4f* gsrc = (const v4f*)(sudoku + base);
    const v4f* grm  = (const v4f*)(rmask  + base);
    v4f s4[NV4], r4[NV4];
    bool act[NV4];
    #pragma unroll
    for (int i = 0; i < NV4; ++i) {
        int g = tid + i * BDIM;
        act[i] = (g < CHUNK / 4);
        if (act[i]) s4[i] = __builtin_nontemporal_load(&gsrc[g]);
    }
    #pragma unroll
    for (int i = 0; i < NV4; ++i) {
        int g = tid + i * BDIM;
        if (act[i]) r4[i] = __builtin_nontemporal_load(&grm[g]);
    }

    // conv weights (9 floats) + bias — L1/L2 broadcast
    float wreg[KK];
    #pragma unroll
    for (int n = 0; n < KK; ++n) wreg[n] = conv_w[n];
    const float bias = conv_b[0];
    const float cmp  = fminf(fmaxf(bias, 0.f), 1.f);   // cell_mask away from chosen cell

    // ---- stage sudoku registers -> LDS (waits only on sudoku vmcnt slice) ----
    v4f* lds4 = (v4f*)lds_s;
    #pragma unroll
    for (int i = 0; i < NV4; ++i) {
        int g = tid + i * BDIM;
        if (act[i]) lds4[g] = s4[i];
    }
    __syncthreads();

    // ---- per-board selection: wave w handles board w ----
    {
        const int wave = tid >> 6;
        const int lane = tid & 63;
        const float* bs = lds_s + wave * BOARD;

        float v0; int i0;
        {
            const int cell = lane;
            float cnt = bias;
            #pragma unroll
            for (int n = 0; n < KK; ++n) cnt += bs[n * CELLS + cell] * wreg[n];
            float nic = fmaxf(cnt - 1.f, 0.f);                       // relu(conv-1)
            float m0  = fminf(fmaxf(1.f - nic, 0.f), 1.f) * (-(float)KK);
            v0 = m0 - nic; i0 = cell;
        }
        if (lane < CELLS - 64) {     // cells 64..80
            const int cell = lane + 64;
            float cnt = bias;
            #pragma unroll
            for (int n = 0; n < KK; ++n) cnt += bs[n * CELLS + cell] * wreg[n];
            float nic = fmaxf(cnt - 1.f, 0.f);
            float m0  = fminf(fmaxf(1.f - nic, 0.f), 1.f) * (-(float)KK);
            float v1 = m0 - nic;
            if (v1 > v0) { v0 = v1; i0 = cell; }   // tie keeps smaller index
        }
        // butterfly argmax-first over 64 lanes (max value; tie -> smaller cell index)
        #pragma unroll
        for (int off = 32; off > 0; off >>= 1) {
            float ov = __shfl_xor(v0, off, 64);
            int   oi = __shfl_xor(i0, off, 64);
            if (ov > v0 || (ov == v0 && oi < i0)) { v0 = ov; i0 = oi; }
        }
        if (lane == 0) {
            const int cell = i0;
            float m = bs[cell]; int nstar = 0;      // first-argmax over numbers
            #pragma unroll
            for (int n = 1; n < KK; ++n) {
                float v = bs[n * CELLS + cell];
                if (v > m) { m = v; nstar = n; }
            }
            meta_e[wave]    = nstar * CELLS + cell;
            meta_cell[wave] = cell;
            meta_m[wave]    = m;
            meta_cms[wave]  = fminf(fmaxf(m * wreg[nstar] + bias, 0.f), 1.f);
            meta_ri[wave]   = rindex[block * BPB + wave];
        }
    }
    __syncthreads();

    // ---- elementwise epilogue from REGISTERS (no LDS board re-read) ----
    v4f* gout_s = (v4f*)(out + base);
    v4f* gout_r = (v4f*)(out + (size_t)Btot * BOARD + base);

    // cell index: f = 4*tid + 1024*i + j; cell = f % 81 (since 729 = 9*81).
    // c0 = (4*tid)%81 once; per (i,j) add {0,52,23}[i]+j then one cond-subtract.
    const int c0 = (4 * tid) % 81;
    const int iadd[NV4] = {0, 52, 23};     // (1024*i) % 81

    #pragma unroll
    for (int i = 0; i < NV4; ++i) {
        int g = tid + i * BDIM;
        if (act[i]) {
            int f0 = 4 * g;                                   // 0..2912
            float so[4], ro[4];
            const float* sp = (const float*)&s4[i];
            const float* rp = (const float*)&r4[i];
            #pragma unroll
            for (int j = 0; j < 4; ++j) {
                int f = f0 + j;
                int blj = (f >= 1458) ? (f >= 2187 ? 3 : 2) : (f >= 729 ? 1 : 0);
                int e = f - blj * BOARD;                      // 0..728 within board
                int cell = c0 + iadd[i] + j;                  // f % 81, folded
                if (cell >= 81) cell -= 81;
                float s  = sp[j];
                float rm = rp[j];
                float m   = meta_m[blj];
                float riv = meta_ri[blj];
                float ov  = (e == meta_e[blj]) ? m : 0.f;                 // one_variant
                float cm  = (cell == meta_cell[blj]) ? meta_cms[blj] : cmp;
                float orm = s * cm * (1.f - ov);                          // one_recursion_mask
                float rmo = fmaxf(rm, riv * orm);
                rmo = fmaxf(rmo, (riv - 1.f) * ov);
                so[j] = s * (1.f - orm);
                ro[j] = rmo;
            }
            v4f sv; sv.x = so[0]; sv.y = so[1]; sv.z = so[2]; sv.w = so[3];
            v4f rv; rv.x = ro[0]; rv.y = ro[1]; rv.z = ro[2]; rv.w = ro[3];
            __builtin_nontemporal_store(sv, &gout_s[g]);
            __builtin_nontemporal_store(rv, &gout_r[g]);
        }
    }

    // recursion_index + 1 output (one float per board)
    if (tid < BPB) {
        out[(size_t)Btot * BOARD * 2 + (size_t)block * BPB + tid] = meta_ri[tid] + 1.f;
    }
}

extern "C" void kernel_launch(void* const* d_in, const int* in_sizes, int n_in,
                              void* d_out, int out_size, void* d_ws, size_t ws_size,
                              hipStream_t stream) {
    const float* sudoku = (const float*)d_in[0];
    const float* rmask  = (const float*)d_in[1];
    const float* rindex = (const float*)d_in[2];
    const float* conv_w = (const float*)d_in[3];
    const float* conv_b = (const float*)d_in[4];
    float* out = (float*)d_out;

    const int Btot = in_sizes[2];            // 32768 boards
    const int nblocks = Btot / BPB;          // 8192

    sudoku_iter_kernel<<<nblocks, BDIM, 0, stream>>>(
        sudoku, rmask, rindex, conv_w, conv_b, out, Btot);
}